// Round 3
// baseline (265.207 us; speedup 1.0000x reference)
//
#include <hip/hip_runtime.h>
#include <cstdint>
#include <cmath>

#define B_   8
#define N_   1024
#define IND  128
#define D_   64
#define H_   4
#define BH_  (B_*H_)

constexpr int MT = 64;        // m-tile
constexpr int NT = N_ / MT;   // 16 tiles
constexpr int RT = 16;        // rows per block (4 waves x 4 rows)

// ---------------- Kernel 1: Ht = H@W (B,H,N,D), e_src, e_dst ----------------
__global__ __launch_bounds__(256) void k_proj(
    const float* __restrict__ H, const float* __restrict__ W,
    const float* __restrict__ a, float* __restrict__ Ht,
    float* __restrict__ esrc, float* __restrict__ edst) {
  __shared__ float hrow[4 * IND];   // 4 rows of H
  const int tid = threadIdx.x;
  const int row0 = blockIdx.x * 4;  // flat row in [0, B*N)
  const float* src = H + (size_t)row0 * IND;
  hrow[tid]       = src[tid];
  hrow[tid + 256] = src[tid + 256];
  __syncthreads();

  const int w = tid >> 6;      // head
  const int lane = tid & 63;   // d
  float acc0 = 0.f, acc1 = 0.f, acc2 = 0.f, acc3 = 0.f;
  #pragma unroll 4
  for (int k = 0; k < IND; ++k) {
    float wk = W[k * 256 + tid];
    acc0 = fmaf(hrow[k],           wk, acc0);
    acc1 = fmaf(hrow[IND + k],     wk, acc1);
    acc2 = fmaf(hrow[2 * IND + k], wk, acc2);
    acc3 = fmaf(hrow[3 * IND + k], wk, acc3);
  }
  const float asrc = a[w * 2 * D_ + lane];
  const float adst = a[w * 2 * D_ + D_ + lane];
  float accs[4] = {acc0, acc1, acc2, acc3};
  #pragma unroll
  for (int r = 0; r < 4; ++r) {
    int row = row0 + r;              // = b*N + n
    int b = row >> 10;
    int n = row & (N_ - 1);
    size_t o = ((size_t)(b * H_ + w) * N_ + n) * D_ + lane;
    Ht[o] = accs[r];
    float es = accs[r] * asrc;
    float ed = accs[r] * adst;
    #pragma unroll
    for (int off = 32; off >= 1; off >>= 1) {
      es += __shfl_xor(es, off);
      ed += __shfl_xor(ed, off);
    }
    if (lane == 0) {
      size_t eo = (size_t)(b * H_ + w) * N_ + n;
      esrc[eo] = es;
      edst[eo] = ed;
    }
  }
}

// ---------------- Kernel 2: flash-style masked softmax + PV ----------------
__global__ __launch_bounds__(256) void k_attn(
    const float* __restrict__ Ht, const float* __restrict__ esrc,
    const float* __restrict__ edst, const int* __restrict__ A,
    float* __restrict__ out) {
  __shared__ float ht[2][MT * D_];   // 2 x 16 KiB double buffer
  __shared__ float pl[MT][20];       // p transpose buffer, padded (16B-aligned groups)

  const int blk = blockIdx.x;
  const int bh = blk >> 6;                 // 64 blocks per (b,h)
  const int n0 = (blk & 63) * RT;
  const int b = bh >> 2, h = bh & 3;
  const int tid = threadIdx.x, w = tid >> 6, lane = tid & 63;
  const float* HtS = Ht + (size_t)bh * N_ * D_;

  const int* Arow[4];
  float es[4], M[4], S[4], acc[4];
  #pragma unroll
  for (int r = 0; r < 4; ++r) {
    int n = n0 + w * 4 + r;
    es[r] = esrc[(size_t)bh * N_ + n];
    Arow[r] = A + ((size_t)b * N_ + n) * N_;
    M[r] = -INFINITY; S[r] = 0.f; acc[r] = 0.f;
  }

  // stage tile 0
  {
    const float4* s4 = (const float4*)HtS;
    float4* d4 = (float4*)ht[0];
    #pragma unroll
    for (int i = 0; i < 4; ++i) d4[tid + 256 * i] = s4[tid + 256 * i];
  }
  __syncthreads();

  int buf = 0;
  for (int t = 0; t < NT; ++t) {
    // prefetch next tile into other buffer
    if (t + 1 < NT) {
      const float4* s4 = (const float4*)(HtS + (size_t)(t + 1) * MT * D_);
      float4* d4 = (float4*)ht[buf ^ 1];
      #pragma unroll
      for (int i = 0; i < 4; ++i) d4[tid + 256 * i] = s4[tid + 256 * i];
    }

    float ed = edst[(size_t)bh * N_ + t * MT + lane];
    #pragma unroll
    for (int r = 0; r < 4; ++r) {
      float s = es[r] + ed;
      s = s > 0.f ? s : 0.2f * s;                 // leaky_relu(0.2)
      int av = Arow[r][t * MT + lane];
      s = (av == 0) ? -1e9f : s;                  // mask
      // tile max
      float m = s;
      #pragma unroll
      for (int off = 32; off >= 1; off >>= 1) m = fmaxf(m, __shfl_xor(m, off));
      float Mn = fmaxf(M[r], m);
      float sc = __expf(M[r] - Mn);               // exp(-inf)=0 first tile
      float p = __expf(s - Mn);
      float ps = p;
      #pragma unroll
      for (int off = 32; off >= 1; off >>= 1) ps += __shfl_xor(ps, off);
      S[r] = S[r] * sc + ps;
      acc[r] *= sc;
      M[r] = Mn;
      pl[lane][w * 4 + r] = p;                    // own wave's column group
    }

    // PV: acc[r] += sum_j p[r][j] * Ht[j][lane]
    const float* hb = ht[buf];
    #pragma unroll 4
    for (int j = 0; j < MT; ++j) {
      float hv = hb[j * D_ + lane];
      float4 pj = *(const float4*)&pl[j][w * 4];  // broadcast, 16B aligned
      acc[0] = fmaf(pj.x, hv, acc[0]);
      acc[1] = fmaf(pj.y, hv, acc[1]);
      acc[2] = fmaf(pj.z, hv, acc[2]);
      acc[3] = fmaf(pj.w, hv, acc[3]);
    }
    __syncthreads();
    buf ^= 1;
  }

  #pragma unroll
  for (int r = 0; r < 4; ++r) {
    int n = n0 + w * 4 + r;
    float o = acc[r] / S[r];
    o = o > 0.f ? o : expm1f(o);                  // elu
    out[((size_t)(b * N_ + n)) * (H_ * D_) + h * D_ + lane] = o;
  }
}

extern "C" void kernel_launch(void* const* d_in, const int* in_sizes, int n_in,
                              void* d_out, int out_size, void* d_ws, size_t ws_size,
                              hipStream_t stream) {
  const float* H = (const float*)d_in[0];
  const int*   A = (const int*)d_in[1];
  const float* W = (const float*)d_in[2];
  const float* a = (const float*)d_in[3];
  float* out = (float*)d_out;

  float* Ht   = (float*)d_ws;                       // B*H*N*D = 2,097,152 f32
  float* esrc = Ht + (size_t)BH_ * N_ * D_;         // 32768 f32
  float* edst = esrc + (size_t)BH_ * N_;            // 32768 f32

  k_proj<<<B_ * N_ / 4, 256, 0, stream>>>(H, W, a, Ht, esrc, edst);
  k_attn<<<BH_ * (N_ / RT), 256, 0, stream>>>(Ht, esrc, edst, A, out);
}

// Round 10
// 143.673 us; speedup vs baseline: 1.8459x; 1.8459x over previous
//
#include <hip/hip_runtime.h>
#include <hip/hip_bf16.h>
#include <cstdint>
#include <cmath>

#define B_   8
#define N_   1024
#define IND  128
#define D_   64
#define H_   4
#define BH_  (B_*H_)

typedef __attribute__((ext_vector_type(8))) short short8;
typedef __attribute__((ext_vector_type(4))) short shortx4;
typedef __attribute__((ext_vector_type(4))) float f32x4;

__device__ inline short f2bf(float f) {
  __hip_bfloat16 h = __float2bfloat16(f);
  return *reinterpret_cast<short*>(&h);
}

// ---------------- Kernel 1: HtT(bf16, [bh][d][m]) = (H@W)^T, e_src, e_dst ---
__global__ __launch_bounds__(256) void k_proj(
    const float* __restrict__ H, const float* __restrict__ W,
    const float* __restrict__ a, short* __restrict__ HtT,
    float* __restrict__ esrc, float* __restrict__ edst) {
  __shared__ float hrow[4 * IND];   // 4 rows of H
  const int tid = threadIdx.x;
  const int row0 = blockIdx.x * 4;  // flat row in [0, B*N)
  const float* src = H + (size_t)row0 * IND;
  hrow[tid]       = src[tid];
  hrow[tid + 256] = src[tid + 256];
  __syncthreads();

  const int w = tid >> 6;      // head
  const int lane = tid & 63;   // d
  float acc0 = 0.f, acc1 = 0.f, acc2 = 0.f, acc3 = 0.f;
  #pragma unroll 4
  for (int k = 0; k < IND; ++k) {
    float wk = W[k * 256 + tid];
    acc0 = fmaf(hrow[k],           wk, acc0);
    acc1 = fmaf(hrow[IND + k],     wk, acc1);
    acc2 = fmaf(hrow[2 * IND + k], wk, acc2);
    acc3 = fmaf(hrow[3 * IND + k], wk, acc3);
  }
  const float asrc = a[w * 2 * D_ + lane];
  const float adst = a[w * 2 * D_ + D_ + lane];
  float accs[4] = {acc0, acc1, acc2, acc3};

  const int b = row0 >> 10;
  const int n = row0 & (N_ - 1);            // 4 consecutive rows, same b
  shortx4 hv;
  #pragma unroll
  for (int r = 0; r < 4; ++r) hv[r] = f2bf(accs[r]);
  *(shortx4*)(HtT + ((size_t)((b * H_ + w) * D_ + lane)) * N_ + n) = hv;

  #pragma unroll
  for (int r = 0; r < 4; ++r) {
    float es = accs[r] * asrc;
    float ed = accs[r] * adst;
    #pragma unroll
    for (int off = 32; off >= 1; off >>= 1) {
      es += __shfl_xor(es, off);
      ed += __shfl_xor(ed, off);
    }
    if (lane == 0) {
      size_t eo = (size_t)(b * H_ + w) * N_ + n + r;
      esrc[eo] = es;
      edst[eo] = ed;
    }
  }
}

// ---------------- Kernel 2: MFMA flash attention, no main-loop LDS ----------
// Block: 16 rows of one (b,h); 4 waves split the m-range (256 each); merge at end.
// A-frag rows are lane&15; C/D-frag rows are (lane>>4)*4+reg (m89 layout) —
// so the online-softmax rescale must be row-remapped via __shfl (the bug fixed here).
__global__ __launch_bounds__(256) void k_attn(
    const short* __restrict__ HtT, const float* __restrict__ esrc,
    const float* __restrict__ edst, const int* __restrict__ A,
    float* __restrict__ out) {
  __shared__ float accL[4][16][68];   // [wave][row][d] padded: 2-way bank alias
  __shared__ float MSl[2][4][16];     // M,S per [wave][row]

  const int blk = blockIdx.x;
  const int bh = blk >> 6;                   // 64 blocks per (b,h)
  const int n0 = (blk & 63) * 16;
  const int b = bh >> 2, h = bh & 3;
  const int tid = threadIdx.x, wv = tid >> 6, lane = tid & 63;
  const int r15 = lane & 15, g = lane >> 4;

  const float* esp = esrc + (size_t)bh * N_;
  const float* edp = edst + (size_t)bh * N_;
  const short* Hp  = HtT + (size_t)bh * D_ * N_;
  const int*   Ap0 = A + (size_t)b * N_ * N_ + (size_t)(n0 + r15) * N_;

  const float es_own = esp[n0 + r15];        // this lane's score-row (A-frag row)

  f32x4 acc[4] = {};                          // 4 d-quadrant C-frags
  float M = -INFINITY, S = 0.f;

  const int mbase = wv * 256;
  for (int c = 0; c < 8; ++c) {
    const int mg = mbase + c * 32 + g * 8;   // this lane's 8 k's (A-frag layout)
    float4 e0 = *(const float4*)(edp + mg);
    float4 e1 = *(const float4*)(edp + mg + 4);
    int4 a0 = *(const int4*)(Ap0 + mg);
    int4 a1 = *(const int4*)(Ap0 + mg + 4);
    float ev[8] = {e0.x, e0.y, e0.z, e0.w, e1.x, e1.y, e1.z, e1.w};
    int   av[8] = {a0.x, a0.y, a0.z, a0.w, a1.x, a1.y, a1.z, a1.w};
    float s[8];
    #pragma unroll
    for (int e = 0; e < 8; ++e) {
      float t = es_own + ev[e];
      t = fmaxf(t, 0.2f * t);                 // leaky_relu(0.2)
      s[e] = av[e] ? t : -1e9f;               // mask
    }
    float m8 = fmaxf(fmaxf(fmaxf(s[0], s[1]), fmaxf(s[2], s[3])),
                     fmaxf(fmaxf(s[4], s[5]), fmaxf(s[6], s[7])));
    m8 = fmaxf(m8, __shfl_xor(m8, 16));       // reduce across the 4 g-lanes
    m8 = fmaxf(m8, __shfl_xor(m8, 32));
    float Mn = fmaxf(M, m8);
    float sc = __expf(M - Mn);                // exp(-inf)=0 on first chunk
    float p[8]; float ps = 0.f;
    #pragma unroll
    for (int e = 0; e < 8; ++e) { p[e] = __expf(s[e] - Mn); ps += p[e]; }
    ps += __shfl_xor(ps, 16);
    ps += __shfl_xor(ps, 32);
    S = S * sc + ps;
    M = Mn;

    // Row-remapped rescale: acc[q][j] belongs to row g*4+j (D layout),
    // whose sc lives in lane g*4+j (rows 0..15 <-> lanes 0..15).
    float scj[4];
    #pragma unroll
    for (int j = 0; j < 4; ++j) scj[j] = __shfl(sc, g * 4 + j);
    #pragma unroll
    for (int q = 0; q < 4; ++q)
      #pragma unroll
      for (int j = 0; j < 4; ++j) acc[q][j] *= scj[j];

    short8 pa;
    #pragma unroll
    for (int e = 0; e < 8; ++e) pa[e] = f2bf(p[e]);
    #pragma unroll
    for (int q = 0; q < 4; ++q) {
      short8 bq = *(const short8*)(Hp + (size_t)(q * 16 + r15) * N_ + mg);
      acc[q] = __builtin_amdgcn_mfma_f32_16x16x32_bf16(pa, bq, acc[q], 0, 0, 0);
    }
  }

  // ---- cross-wave online-softmax merge ----
  #pragma unroll
  for (int q = 0; q < 4; ++q)
    #pragma unroll
    for (int j = 0; j < 4; ++j)
      accL[wv][g * 4 + j][q * 16 + r15] = acc[q][j];   // C-frag: row=g*4+j, col=r15
  if (g == 0) { MSl[0][wv][r15] = M; MSl[1][wv][r15] = S; }
  __syncthreads();

  const int row = tid >> 4, d0 = (tid & 15) * 4;
  float Mw[4], Sw[4], Mg = -INFINITY;
  #pragma unroll
  for (int w = 0; w < 4; ++w) {
    Mw[w] = MSl[0][w][row]; Sw[w] = MSl[1][w][row];
    Mg = fmaxf(Mg, Mw[w]);
  }
  float Sg = 0.f;
  float o[4] = {0.f, 0.f, 0.f, 0.f};
  #pragma unroll
  for (int w = 0; w < 4; ++w) {
    float f = __expf(Mw[w] - Mg);
    Sg += Sw[w] * f;
    float4 av = *(const float4*)&accL[w][row][d0];
    o[0] = fmaf(av.x, f, o[0]); o[1] = fmaf(av.y, f, o[1]);
    o[2] = fmaf(av.z, f, o[2]); o[3] = fmaf(av.w, f, o[3]);
  }
  const float inv = 1.f / Sg;
  float4 ov;
  float vx = o[0] * inv; ov.x = vx > 0.f ? vx : expm1f(vx);
  float vy = o[1] * inv; ov.y = vy > 0.f ? vy : expm1f(vy);
  float vz = o[2] * inv; ov.z = vz > 0.f ? vz : expm1f(vz);
  float vw = o[3] * inv; ov.w = vw > 0.f ? vw : expm1f(vw);
  *(float4*)(out + ((size_t)(b * N_ + n0 + row)) * (H_ * D_) + h * D_ + d0) = ov;
}

extern "C" void kernel_launch(void* const* d_in, const int* in_sizes, int n_in,
                              void* d_out, int out_size, void* d_ws, size_t ws_size,
                              hipStream_t stream) {
  const float* H = (const float*)d_in[0];
  const int*   A = (const int*)d_in[1];
  const float* W = (const float*)d_in[2];
  const float* a = (const float*)d_in[3];
  float* out = (float*)d_out;

  short* HtT  = (short*)d_ws;                                   // 4 MB bf16
  float* esrc = (float*)((char*)d_ws + (size_t)BH_ * D_ * N_ * 2);
  float* edst = esrc + (size_t)BH_ * N_;

  k_proj<<<B_ * N_ / 4, 256, 0, stream>>>(H, W, a, HtT, esrc, edst);
  k_attn<<<BH_ * (N_ / 16), 256, 0, stream>>>(HtT, esrc, edst, A, out);
}

// Round 13
// 143.451 us; speedup vs baseline: 1.8488x; 1.0015x over previous
//
#include <hip/hip_runtime.h>
#include <hip/hip_bf16.h>
#include <cstdint>
#include <cmath>

#define B_   8
#define N_   1024
#define IND  128
#define D_   64
#define H_   4
#define BH_  (B_*H_)

typedef __attribute__((ext_vector_type(8))) short short8;
typedef __attribute__((ext_vector_type(4))) short shortx4;
typedef __attribute__((ext_vector_type(4))) float f32x4;

__device__ inline short f2bf(float f) {
  __hip_bfloat16 h = __float2bfloat16(f);
  return *reinterpret_cast<short*>(&h);
}

// ---------------- Kernel 1: HtT(bf16, [bh][d][m]) = (H@W)^T, e_src, e_dst ---
// (round-10 validated form, byte-identical)
__global__ __launch_bounds__(256) void k_proj(
    const float* __restrict__ H, const float* __restrict__ W,
    const float* __restrict__ a, short* __restrict__ HtT,
    float* __restrict__ esrc, float* __restrict__ edst) {
  __shared__ float hrow[4 * IND];   // 4 rows of H
  const int tid = threadIdx.x;
  const int row0 = blockIdx.x * 4;  // flat row in [0, B*N)
  const float* src = H + (size_t)row0 * IND;
  hrow[tid]       = src[tid];
  hrow[tid + 256] = src[tid + 256];
  __syncthreads();

  const int w = tid >> 6;      // head
  const int lane = tid & 63;   // d
  float acc0 = 0.f, acc1 = 0.f, acc2 = 0.f, acc3 = 0.f;
  #pragma unroll 4
  for (int k = 0; k < IND; ++k) {
    float wk = W[k * 256 + tid];
    acc0 = fmaf(hrow[k],           wk, acc0);
    acc1 = fmaf(hrow[IND + k],     wk, acc1);
    acc2 = fmaf(hrow[2 * IND + k], wk, acc2);
    acc3 = fmaf(hrow[3 * IND + k], wk, acc3);
  }
  const float asrc = a[w * 2 * D_ + lane];
  const float adst = a[w * 2 * D_ + D_ + lane];
  float accs[4] = {acc0, acc1, acc2, acc3};

  const int b = row0 >> 10;
  const int n = row0 & (N_ - 1);            // 4 consecutive rows, same b
  shortx4 hv;
  #pragma unroll
  for (int r = 0; r < 4; ++r) hv[r] = f2bf(accs[r]);
  *(shortx4*)(HtT + ((size_t)((b * H_ + w) * D_ + lane)) * N_ + n) = hv;

  #pragma unroll
  for (int r = 0; r < 4; ++r) {
    float es = accs[r] * asrc;
    float ed = accs[r] * adst;
    #pragma unroll
    for (int off = 32; off >= 1; off >>= 1) {
      es += __shfl_xor(es, off);
      ed += __shfl_xor(ed, off);
    }
    if (lane == 0) {
      size_t eo = (size_t)(b * H_ + w) * N_ + n + r;
      esrc[eo] = es;
      edst[eo] = ed;
    }
  }
}

// ---------------- Kernel 2: MFMA attention, two-pass exact softmax ----------
// Pass 1: all 64 masked scores of this lane into s[8][8] (registers).
// One max-reduce (local tree + 2 shfl) -> true row max M for this wave's m-range.
// Pass 2: p = exp(s - M), pack bf16, MFMA. No online rescale at all.
// Cross-wave merge identical to the validated round-10 form (per-wave M,S).
__global__ __launch_bounds__(256) void k_attn(
    const short* __restrict__ HtT, const float* __restrict__ esrc,
    const float* __restrict__ edst, const int* __restrict__ A,
    float* __restrict__ out) {
  __shared__ float accL[4][16][68];   // [wave][row][d] padded
  __shared__ float MSl[2][4][16];     // M,S per [wave][row]

  const int blk = blockIdx.x;
  const int bh = blk >> 6;                   // 64 blocks per (b,h)
  const int n0 = (blk & 63) * 16;
  const int b = bh >> 2, h = bh & 3;
  const int tid = threadIdx.x, wv = tid >> 6, lane = tid & 63;
  const int r15 = lane & 15, g = lane >> 4;

  const float* edp = edst + (size_t)bh * N_;
  const short* Hp  = HtT + (size_t)bh * D_ * N_;
  const int*   Ap0 = A + (size_t)b * N_ * N_ + (size_t)(n0 + r15) * N_;

  const float es_own = esrc[(size_t)bh * N_ + n0 + r15];  // A-frag row = lane&15

  const int mbase = wv * 256;

  // ---- pass 1: scores ----
  float s[8][8];
  #pragma unroll
  for (int c = 0; c < 8; ++c) {
    const int mg = mbase + c * 32 + g * 8;   // this lane's 8 k's (A-frag layout)
    float4 e0 = *(const float4*)(edp + mg);
    float4 e1 = *(const float4*)(edp + mg + 4);
    int4 a0 = *(const int4*)(Ap0 + mg);
    int4 a1 = *(const int4*)(Ap0 + mg + 4);
    float ev[8] = {e0.x, e0.y, e0.z, e0.w, e1.x, e1.y, e1.z, e1.w};
    int   av[8] = {a0.x, a0.y, a0.z, a0.w, a1.x, a1.y, a1.z, a1.w};
    #pragma unroll
    for (int e = 0; e < 8; ++e) {
      float t = es_own + ev[e];
      t = fmaxf(t, 0.2f * t);                 // leaky_relu(0.2)
      s[c][e] = av[e] ? t : -1e9f;            // mask
    }
  }

  // ---- one max reduction: true row max over this wave's 256 m's ----
  float M = -INFINITY;
  #pragma unroll
  for (int c = 0; c < 8; ++c)
    #pragma unroll
    for (int e = 0; e < 8; ++e) M = fmaxf(M, s[c][e]);
  M = fmaxf(M, __shfl_xor(M, 16));
  M = fmaxf(M, __shfl_xor(M, 32));

  // ---- pass 2: exp + MFMA, fixed M ----
  f32x4 acc[4] = {};
  float psum = 0.f;
  #pragma unroll
  for (int c = 0; c < 8; ++c) {
    const int mg = mbase + c * 32 + g * 8;
    short8 pa;
    #pragma unroll
    for (int e = 0; e < 8; ++e) {
      float p = __expf(s[c][e] - M);
      psum += p;
      pa[e] = f2bf(p);
    }
    #pragma unroll
    for (int q = 0; q < 4; ++q) {
      short8 bq = *(const short8*)(Hp + (size_t)(q * 16 + r15) * N_ + mg);
      acc[q] = __builtin_amdgcn_mfma_f32_16x16x32_bf16(pa, bq, acc[q], 0, 0, 0);
    }
  }
  psum += __shfl_xor(psum, 16);
  psum += __shfl_xor(psum, 32);

  // ---- cross-wave online-softmax merge (round-10 validated form) ----
  #pragma unroll
  for (int q = 0; q < 4; ++q)
    #pragma unroll
    for (int j = 0; j < 4; ++j)
      accL[wv][g * 4 + j][q * 16 + r15] = acc[q][j];   // C-frag: row=g*4+j, col=r15
  if (g == 0) { MSl[0][wv][r15] = M; MSl[1][wv][r15] = psum; }
  __syncthreads();

  const int row = tid >> 4, d0 = (tid & 15) * 4;
  float Mw[4], Sw[4], Mg = -INFINITY;
  #pragma unroll
  for (int w = 0; w < 4; ++w) {
    Mw[w] = MSl[0][w][row]; Sw[w] = MSl[1][w][row];
    Mg = fmaxf(Mg, Mw[w]);
  }
  float Sg = 0.f;
  float o[4] = {0.f, 0.f, 0.f, 0.f};
  #pragma unroll
  for (int w = 0; w < 4; ++w) {
    float f = __expf(Mw[w] - Mg);
    Sg += Sw[w] * f;
    float4 av = *(const float4*)&accL[w][row][d0];
    o[0] = fmaf(av.x, f, o[0]); o[1] = fmaf(av.y, f, o[1]);
    o[2] = fmaf(av.z, f, o[2]); o[3] = fmaf(av.w, f, o[3]);
  }
  const float inv = 1.f / Sg;
  float4 ov;
  float vx = o[0] * inv; ov.x = vx > 0.f ? vx : expm1f(vx);
  float vy = o[1] * inv; ov.y = vy > 0.f ? vy : expm1f(vy);
  float vz = o[2] * inv; ov.z = vz > 0.f ? vz : expm1f(vz);
  float vw = o[3] * inv; ov.w = vw > 0.f ? vw : expm1f(vw);
  *(float4*)(out + ((size_t)(b * N_ + n0 + row)) * (H_ * D_) + h * D_ + d0) = ov;
}

extern "C" void kernel_launch(void* const* d_in, const int* in_sizes, int n_in,
                              void* d_out, int out_size, void* d_ws, size_t ws_size,
                              hipStream_t stream) {
  const float* H = (const float*)d_in[0];
  const int*   A = (const int*)d_in[1];
  const float* W = (const float*)d_in[2];
  const float* a = (const float*)d_in[3];
  float* out = (float*)d_out;

  short* HtT  = (short*)d_ws;                                   // 4 MB bf16
  float* esrc = (float*)((char*)d_ws + (size_t)BH_ * D_ * N_ * 2);
  float* edst = esrc + (size_t)BH_ * N_;

  k_proj<<<B_ * N_ / 4, 256, 0, stream>>>(H, W, a, HtT, esrc, edst);
  k_attn<<<BH_ * (N_ / 16), 256, 0, stream>>>(HtT, esrc, edst, A, out);
}

// Round 14
// 143.352 us; speedup vs baseline: 1.8500x; 1.0007x over previous
//
#include <hip/hip_runtime.h>
#include <hip/hip_bf16.h>
#include <cstdint>
#include <cmath>

#define B_   8
#define N_   1024
#define IND  128
#define D_   64
#define H_   4
#define BH_  (B_*H_)

typedef __attribute__((ext_vector_type(8))) short short8;
typedef __attribute__((ext_vector_type(4))) short shortx4;
typedef __attribute__((ext_vector_type(4))) float f32x4;

__device__ inline short f2bf(float f) {
  __hip_bfloat16 h = __float2bfloat16(f);
  return *reinterpret_cast<short*>(&h);
}

// ---------------- Kernel 0: pack A (int32 0/1) into bitmask ----------------
// Abits[row][c] (u64) bit i = (A[row][c*64+i] != 0); row = b*N + n.
__global__ __launch_bounds__(256) void k_pack(
    const int* __restrict__ A, unsigned long long* __restrict__ Abits) {
  const int tid = threadIdx.x, wv = tid >> 6, lane = tid & 63;
  const int row = blockIdx.x * 4 + wv;           // [0, B*N)
  const int* Ar = A + (size_t)row * N_;
  unsigned long long* Out = Abits + (size_t)row * 16;
  #pragma unroll
  for (int c = 0; c < 16; ++c) {
    int v = Ar[c * 64 + lane];
    unsigned long long bits = __ballot(v != 0);
    if (lane == 0) Out[c] = bits;
  }
}

// ---------------- Kernel 1: HtT(bf16, [bh][d][m]) = (H@W)^T, e_src, e_dst ---
// (round-13 validated form, byte-identical)
__global__ __launch_bounds__(256) void k_proj(
    const float* __restrict__ H, const float* __restrict__ W,
    const float* __restrict__ a, short* __restrict__ HtT,
    float* __restrict__ esrc, float* __restrict__ edst) {
  __shared__ float hrow[4 * IND];   // 4 rows of H
  const int tid = threadIdx.x;
  const int row0 = blockIdx.x * 4;  // flat row in [0, B*N)
  const float* src = H + (size_t)row0 * IND;
  hrow[tid]       = src[tid];
  hrow[tid + 256] = src[tid + 256];
  __syncthreads();

  const int w = tid >> 6;      // head
  const int lane = tid & 63;   // d
  float acc0 = 0.f, acc1 = 0.f, acc2 = 0.f, acc3 = 0.f;
  #pragma unroll 4
  for (int k = 0; k < IND; ++k) {
    float wk = W[k * 256 + tid];
    acc0 = fmaf(hrow[k],           wk, acc0);
    acc1 = fmaf(hrow[IND + k],     wk, acc1);
    acc2 = fmaf(hrow[2 * IND + k], wk, acc2);
    acc3 = fmaf(hrow[3 * IND + k], wk, acc3);
  }
  const float asrc = a[w * 2 * D_ + lane];
  const float adst = a[w * 2 * D_ + D_ + lane];
  float accs[4] = {acc0, acc1, acc2, acc3};

  const int b = row0 >> 10;
  const int n = row0 & (N_ - 1);            // 4 consecutive rows, same b
  shortx4 hv;
  #pragma unroll
  for (int r = 0; r < 4; ++r) hv[r] = f2bf(accs[r]);
  *(shortx4*)(HtT + ((size_t)((b * H_ + w) * D_ + lane)) * N_ + n) = hv;

  #pragma unroll
  for (int r = 0; r < 4; ++r) {
    float es = accs[r] * asrc;
    float ed = accs[r] * adst;
    #pragma unroll
    for (int off = 32; off >= 1; off >>= 1) {
      es += __shfl_xor(es, off);
      ed += __shfl_xor(ed, off);
    }
    if (lane == 0) {
      size_t eo = (size_t)(b * H_ + w) * N_ + n + r;
      esrc[eo] = es;
      edst[eo] = ed;
    }
  }
}

// ---------------- Kernel 2: MFMA attention, two-pass exact softmax ----------
// XCD-affinity swizzle: all 64 blocks of one (b,h) share blk%8, i.e. one XCD,
// so HtT[bh] (128 KB) stays in that XCD's L2. Pure permutation of blockIdx.
// A is consumed as a bitmask (1 u32 per chunk, L1-hot) instead of 2 int4 HBM loads.
__global__ __launch_bounds__(256) void k_attn(
    const short* __restrict__ HtT, const float* __restrict__ esrc,
    const float* __restrict__ edst, const unsigned* __restrict__ Abits,
    float* __restrict__ out) {
  __shared__ float accL[4][16][68];   // [wave][row][d] padded
  __shared__ float MSl[2][4][16];     // M,S per [wave][row]

  const int blk = blockIdx.x;
  const int x = blk & 7, y = blk >> 3;       // XCD swizzle (bijective)
  const int bh = (y & 3) * 8 + x;            // bh % 8 == blk % 8
  const int n0 = (y >> 2) * 16;
  const int b = bh >> 2, h = bh & 3;
  const int tid = threadIdx.x, wv = tid >> 6, lane = tid & 63;
  const int r15 = lane & 15, g = lane >> 4;

  const float* edp = edst + (size_t)bh * N_;
  const short* Hp  = HtT + (size_t)bh * D_ * N_;
  const unsigned* Abp = Abits + ((size_t)(b * N_ + n0 + r15)) * 32;  // u32/32 m's

  const float es_own = esrc[(size_t)bh * N_ + n0 + r15];  // A-frag row = lane&15
  const int gs = g * 8;

  const int mbase = wv * 256;

  // ---- pass 1: scores ----
  float s[8][8];
  #pragma unroll
  for (int c = 0; c < 8; ++c) {
    const int mg = mbase + c * 32 + gs;      // this lane's 8 k's (A-frag layout)
    float4 e0 = *(const float4*)(edp + mg);
    float4 e1 = *(const float4*)(edp + mg + 4);
    unsigned ab = Abp[wv * 8 + c] >> gs;     // bits for m = mg..mg+7
    float ev[8] = {e0.x, e0.y, e0.z, e0.w, e1.x, e1.y, e1.z, e1.w};
    #pragma unroll
    for (int e = 0; e < 8; ++e) {
      float t = es_own + ev[e];
      t = fmaxf(t, 0.2f * t);                 // leaky_relu(0.2)
      s[c][e] = ((ab >> e) & 1u) ? t : -1e9f; // mask
    }
  }

  // ---- one max reduction: true row max over this wave's 256 m's ----
  float M = -INFINITY;
  #pragma unroll
  for (int c = 0; c < 8; ++c)
    #pragma unroll
    for (int e = 0; e < 8; ++e) M = fmaxf(M, s[c][e]);
  M = fmaxf(M, __shfl_xor(M, 16));
  M = fmaxf(M, __shfl_xor(M, 32));

  // ---- pass 2: exp + MFMA, fixed M ----
  f32x4 acc[4] = {};
  float psum = 0.f;
  #pragma unroll
  for (int c = 0; c < 8; ++c) {
    const int mg = mbase + c * 32 + gs;
    short8 pa;
    #pragma unroll
    for (int e = 0; e < 8; ++e) {
      float p = __expf(s[c][e] - M);
      psum += p;
      pa[e] = f2bf(p);
    }
    #pragma unroll
    for (int q = 0; q < 4; ++q) {
      short8 bq = *(const short8*)(Hp + (size_t)(q * 16 + r15) * N_ + mg);
      acc[q] = __builtin_amdgcn_mfma_f32_16x16x32_bf16(pa, bq, acc[q], 0, 0, 0);
    }
  }
  psum += __shfl_xor(psum, 16);
  psum += __shfl_xor(psum, 32);

  // ---- cross-wave online-softmax merge (validated form) ----
  #pragma unroll
  for (int q = 0; q < 4; ++q)
    #pragma unroll
    for (int j = 0; j < 4; ++j)
      accL[wv][g * 4 + j][q * 16 + r15] = acc[q][j];   // C-frag: row=g*4+j, col=r15
  if (g == 0) { MSl[0][wv][r15] = M; MSl[1][wv][r15] = psum; }
  __syncthreads();

  const int row = tid >> 4, d0 = (tid & 15) * 4;
  float Mw[4], Sw[4], Mg = -INFINITY;
  #pragma unroll
  for (int w = 0; w < 4; ++w) {
    Mw[w] = MSl[0][w][row]; Sw[w] = MSl[1][w][row];
    Mg = fmaxf(Mg, Mw[w]);
  }
  float Sg = 0.f;
  float o[4] = {0.f, 0.f, 0.f, 0.f};
  #pragma unroll
  for (int w = 0; w < 4; ++w) {
    float f = __expf(Mw[w] - Mg);
    Sg += Sw[w] * f;
    float4 av = *(const float4*)&accL[w][row][d0];
    o[0] = fmaf(av.x, f, o[0]); o[1] = fmaf(av.y, f, o[1]);
    o[2] = fmaf(av.z, f, o[2]); o[3] = fmaf(av.w, f, o[3]);
  }
  const float inv = 1.f / Sg;
  float4 ov;
  float vx = o[0] * inv; ov.x = vx > 0.f ? vx : expm1f(vx);
  float vy = o[1] * inv; ov.y = vy > 0.f ? vy : expm1f(vy);
  float vz = o[2] * inv; ov.z = vz > 0.f ? vz : expm1f(vz);
  float vw = o[3] * inv; ov.w = vw > 0.f ? vw : expm1f(vw);
  *(float4*)(out + ((size_t)(b * N_ + n0 + row)) * (H_ * D_) + h * D_ + d0) = ov;
}

extern "C" void kernel_launch(void* const* d_in, const int* in_sizes, int n_in,
                              void* d_out, int out_size, void* d_ws, size_t ws_size,
                              hipStream_t stream) {
  const float* H = (const float*)d_in[0];
  const int*   A = (const int*)d_in[1];
  const float* W = (const float*)d_in[2];
  const float* a = (const float*)d_in[3];
  float* out = (float*)d_out;

  short* HtT  = (short*)d_ws;                                   // 4 MB bf16
  float* esrc = (float*)((char*)d_ws + (size_t)BH_ * D_ * N_ * 2);
  float* edst = esrc + (size_t)BH_ * N_;
  unsigned long long* Abits =
      (unsigned long long*)(edst + (size_t)BH_ * N_);           // 1 MB

  k_pack<<<B_ * N_ / 4, 256, 0, stream>>>(A, Abits);
  k_proj<<<B_ * N_ / 4, 256, 0, stream>>>(H, W, a, HtT, esrc, edst);
  k_attn<<<BH_ * (N_ / 16), 256, 0, stream>>>(HtT, esrc, edst,
                                              (const unsigned*)Abits, out);
}